// Round 4
// baseline (273.453 us; speedup 1.0000x reference)
//
#include <hip/hip_runtime.h>

// Problem: B=16, C=384, H=W=64, G=48 groups (8 ch/group), K=3 gaussian, sigma=0.5
#define B_   16
#define C_   384
#define H_   64
#define W_   64
#define G_   48
#define PLANE (H_ * W_)   // 4096
#define SCOLS 67          // 66 used cols (0..65) + 1 pad col -> odd stride, no conflicts
#define SROWS 66
#define SELEM (SROWS * SCOLS)

// One block per (batch, group): processes 8 contiguous channel planes that all
// share the same integer shift and gaussian weights. Software-pipelined:
// while computing plane i from LDS buf (i&1), the 16 staging loads for plane
// i+1 are in flight, drained into buf ((i+1)&1) afterwards. buf ((i+1)&1) was
// last READ during compute(i-1), which completed before the previous barrier,
// so the drain is race-free with a single barrier per plane.
__global__ __launch_bounds__(256) void displace_fused_pipe(
    const float* __restrict__ inp,     // [B,C,H,W]
    const float* __restrict__ offset,  // [G,2] (x,y)
    float* __restrict__ out0,          // displaced
    float* __restrict__ out1)          // blurred
{
    __shared__ float s[2][SELEM];

    const int tid = threadIdx.x;
    const int g   = blockIdx.x % G_;
    const int b   = blockIdx.x / G_;

    // shift + separable 3x3 weights, computed redundantly per thread (uniform)
    const float ofx = offset[2 * g + 0];
    const float ofy = offset[2 * g + 1];
    const float rx = rintf(ofx);      // half-even == jnp.round; no ties (noise ±0.45)
    const float ry = rintf(ofy);
    const float fx = ofx - rx;
    const float fy = ofy - ry;
    const int ox = (int)rx;
    const int oy = (int)ry;

    float w[9];
    {
        float sum = 0.0f;
        #pragma unroll
        for (int i = 0; i < 3; ++i) {
            const float dy = (float)(i - 1) + fy;
            #pragma unroll
            for (int j = 0; j < 3; ++j) {
                const float dx = (float)(j - 1) + fx;
                const float v = __expf(-(dx * dx + dy * dy) * 2.0f); // 1/(2*sigma^2)=2
                w[i * 3 + j] = v;
                sum += v;
            }
        }
        const float inv = 1.0f / sum;
        #pragma unroll
        for (int k = 0; k < 9; ++k) w[k] *= inv;
    }

    // Zero the halo of BOTH buffers once; interior writes never touch it.
    // Live halo: rows 0 & 65 (cols 0..65) and cols 0 & 65 (rows 1..64).
    #pragma unroll
    for (int bb = 0; bb < 2; ++bb) {
        if (tid < 67) { s[bb][tid] = 0.0f; s[bb][65 * SCOLS + tid] = 0.0f; }
        if (tid < 64) { s[bb][(tid + 1) * SCOLS] = 0.0f; s[bb][(tid + 1) * SCOLS + 65] = 0.0f; }
    }

    const int lane = tid & 63;
    const int wv   = tid >> 6;           // wave handles rows wv, wv+4, ...
    const int sx   = lane - ox;
    const bool vx  = (unsigned)sx < (unsigned)W_;

    const float* __restrict__ base = inp + ((size_t)b * C_ + (size_t)g * 8) * PLANE;
    float* __restrict__ ob0 = out0 + ((size_t)b * C_ + (size_t)g * 8) * PLANE;
    float* __restrict__ ob1 = out1 + ((size_t)b * C_ + (size_t)g * 8) * PLANE;

    // Stage plane 0 into buf 0
    float v[16];
    #pragma unroll
    for (int k = 0; k < 16; ++k) {
        const int y  = (k << 2) + wv;
        const int sy = y - oy;
        v[k] = (vx && (unsigned)sy < (unsigned)H_) ? base[sy * W_ + sx] : 0.0f;
    }
    #pragma unroll
    for (int k = 0; k < 16; ++k) {
        const int y = (k << 2) + wv;
        s[0][(y + 1) * SCOLS + 1 + lane] = v[k];
    }
    __syncthreads();

    #pragma unroll
    for (int i = 0; i < 8; ++i) {
        // Issue next plane's loads FIRST so they are in flight during compute.
        if (i < 7) {
            const float* __restrict__ plane = base + (size_t)(i + 1) * PLANE;
            #pragma unroll
            for (int k = 0; k < 16; ++k) {
                const int y  = (k << 2) + wv;
                const int sy = y - oy;
                v[k] = (vx && (unsigned)sy < (unsigned)H_) ? plane[sy * W_ + sx] : 0.0f;
            }
        }

        // Compute + store plane i from buf (i&1). 4 px per thread per iter.
        const float* __restrict__ sb = s[i & 1];
        float* __restrict__ o0 = ob0 + (size_t)i * PLANE;
        float* __restrict__ o1 = ob1 + (size_t)i * PLANE;
        #pragma unroll
        for (int it = 0; it < 4; ++it) {
            const int pbase = it * 1024 + tid * 4;
            const int y = pbase >> 6;
            const int x = pbase & 63;
            const float* r0 = &sb[y * SCOLS + x];   // rows y..y+2, cols x..x+5
            const float* r1 = r0 + SCOLS;
            const float* r2 = r1 + SCOLS;

            float p0[6], p1[6], p2[6];
            #pragma unroll
            for (int j = 0; j < 6; ++j) { p0[j] = r0[j]; p1[j] = r1[j]; p2[j] = r2[j]; }

            const float4 d0 = make_float4(p1[1], p1[2], p1[3], p1[4]);

            float a0, a1, a2, a3;
            a0 = p0[0]*w[0] + p0[1]*w[1] + p0[2]*w[2]
               + p1[0]*w[3] + p1[1]*w[4] + p1[2]*w[5]
               + p2[0]*w[6] + p2[1]*w[7] + p2[2]*w[8];
            a1 = p0[1]*w[0] + p0[2]*w[1] + p0[3]*w[2]
               + p1[1]*w[3] + p1[2]*w[4] + p1[3]*w[5]
               + p2[1]*w[6] + p2[2]*w[7] + p2[3]*w[8];
            a2 = p0[2]*w[0] + p0[3]*w[1] + p0[4]*w[2]
               + p1[2]*w[3] + p1[3]*w[4] + p1[4]*w[5]
               + p2[2]*w[6] + p2[3]*w[7] + p2[4]*w[8];
            a3 = p0[3]*w[0] + p0[4]*w[1] + p0[5]*w[2]
               + p1[3]*w[3] + p1[4]*w[4] + p1[5]*w[5]
               + p2[3]*w[6] + p2[4]*w[7] + p2[5]*w[8];

            *(float4*)(o0 + pbase) = d0;
            *(float4*)(o1 + pbase) = make_float4(a0, a1, a2, a3);
        }

        // Drain next plane's registers into the other buffer, then barrier.
        if (i < 7) {
            float* __restrict__ sw = s[(i + 1) & 1];
            #pragma unroll
            for (int k = 0; k < 16; ++k) {
                const int y = (k << 2) + wv;
                sw[(y + 1) * SCOLS + 1 + lane] = v[k];
            }
            __syncthreads();
        }
    }
}

extern "C" void kernel_launch(void* const* d_in, const int* in_sizes, int n_in,
                              void* d_out, int out_size, void* d_ws, size_t ws_size,
                              hipStream_t stream) {
    const float* inp    = (const float*)d_in[0];
    const float* offset = (const float*)d_in[1];
    float* out0 = (float*)d_out;
    float* out1 = out0 + (size_t)B_ * C_ * PLANE;
    displace_fused_pipe<<<B_ * G_, 256, 0, stream>>>(inp, offset, out0, out1);
}

// Round 5
// 272.928 us; speedup vs baseline: 1.0019x; 1.0019x over previous
//
#include <hip/hip_runtime.h>

// Problem: B=16, C=384, H=W=64, G=48 groups (8 ch/group), K=3 gaussian, sigma=0.5
#define B_   16
#define C_   384
#define H_   64
#define W_   64
#define G_   48
#define PLANE (H_ * W_)   // 4096
#define SCOLS 67          // 66 used cols (0..65) + 1 pad col -> odd stride
#define SROWS 66
#define SELEM (SROWS * SCOLS)

// One block per (batch, group): 8 contiguous channel planes sharing one shift
// + gaussian. Double-buffered LDS; loads for plane i+1 issued before compute
// of plane i. Compute mapping: x = lane (lane-stride-4B LDS reads -> 2-way
// bank aliasing only, which is free), 16 vertical rows per thread, separable
// gaussian with a rolling horizontal-sum ring (3 LDS reads + 6 FMA per px).
__global__ __launch_bounds__(256) void displace_fused_pipe(
    const float* __restrict__ inp,     // [B,C,H,W]
    const float* __restrict__ offset,  // [G,2] (x,y)
    float* __restrict__ out0,          // displaced
    float* __restrict__ out1)          // blurred
{
    __shared__ float s[2][SELEM];

    const int tid = threadIdx.x;
    const int g   = blockIdx.x % G_;
    const int b   = blockIdx.x / G_;

    const float ofx = offset[2 * g + 0];
    const float ofy = offset[2 * g + 1];
    const float rx = rintf(ofx);      // half-even == jnp.round; no ties (noise ±0.45)
    const float ry = rintf(ofy);
    const float fx = ofx - rx;
    const float fy = ofy - ry;
    const int ox = (int)rx;
    const int oy = (int)ry;

    // Separable, separately-normalized gaussian taps:
    // kern[i][j]/sum == (wy[i]/Sy) * (wx[j]/Sx) since sum = Sy*Sx.
    float wx[3], wy[3];
    {
        float sxs = 0.0f, sys = 0.0f;
        #pragma unroll
        for (int j = 0; j < 3; ++j) {
            const float dx = (float)(j - 1) + fx;
            const float dy = (float)(j - 1) + fy;
            wx[j] = __expf(-dx * dx * 2.0f);   // 1/(2*sigma^2) = 2
            wy[j] = __expf(-dy * dy * 2.0f);
            sxs += wx[j]; sys += wy[j];
        }
        const float ix = 1.0f / sxs, iy = 1.0f / sys;
        #pragma unroll
        for (int j = 0; j < 3; ++j) { wx[j] *= ix; wy[j] *= iy; }
    }

    // Zero the halo of BOTH buffers once (rows 0 & 65 cols 0..65; cols 0 & 65
    // rows 1..64). Interior is fully overwritten by staging (OOB lanes write 0).
    #pragma unroll
    for (int bb = 0; bb < 2; ++bb) {
        if (tid < 66) { s[bb][tid] = 0.0f; s[bb][65 * SCOLS + tid] = 0.0f; }
        if (tid < 64) { s[bb][(tid + 1) * SCOLS] = 0.0f; s[bb][(tid + 1) * SCOLS + 65] = 0.0f; }
    }

    const int lane = tid & 63;
    const int wv   = tid >> 6;           // wave id 0..3
    const int sx   = lane - ox;
    const bool vx  = (unsigned)sx < (unsigned)W_;

    const float* __restrict__ base = inp + ((size_t)b * C_ + (size_t)g * 8) * PLANE;
    float* __restrict__ ob0 = out0 + ((size_t)b * C_ + (size_t)g * 8) * PLANE;
    float* __restrict__ ob1 = out1 + ((size_t)b * C_ + (size_t)g * 8) * PLANE;

    // Stage plane 0 into buf 0 (16 outstanding loads per wave, then drain).
    float v[16];
    #pragma unroll
    for (int k = 0; k < 16; ++k) {
        const int y  = (k << 2) + wv;
        const int sy = y - oy;
        v[k] = (vx && (unsigned)sy < (unsigned)H_) ? base[sy * W_ + sx] : 0.0f;
    }
    #pragma unroll
    for (int k = 0; k < 16; ++k) {
        const int y = (k << 2) + wv;
        s[0][(y + 1) * SCOLS + 1 + lane] = v[k];
    }
    __syncthreads();

    const int x  = lane;        // output column handled by this thread
    const int y0 = wv << 4;     // 16 output rows per thread: y0 .. y0+15

    #pragma unroll
    for (int i = 0; i < 8; ++i) {
        // Issue next plane's loads FIRST so they are in flight during compute.
        if (i < 7) {
            const float* __restrict__ plane = base + (size_t)(i + 1) * PLANE;
            #pragma unroll
            for (int k = 0; k < 16; ++k) {
                const int y  = (k << 2) + wv;
                const int sy = y - oy;
                v[k] = (vx && (unsigned)sy < (unsigned)H_) ? plane[sy * W_ + sx] : 0.0f;
            }
        }

        // Compute + store plane i from buf (i&1).
        const float* __restrict__ sb = s[i & 1];
        float* __restrict__ o0 = ob0 + (size_t)i * PLANE;
        float* __restrict__ o1 = ob1 + (size_t)i * PLANE;

        // Window for output row r uses tile rows r..r+2 at cols x..x+2.
        // Rolling ring of horizontal sums H(tile row); center tap = displaced.
        const float* rp;
        rp = &sb[y0 * SCOLS + x];              // tile row y0 (= output row y0-1)
        float Hm = rp[0] * wx[0] + rp[1] * wx[1] + rp[2] * wx[2];
        rp = &sb[(y0 + 1) * SCOLS + x];        // tile row y0+1 (= output row y0)
        float c0 = rp[1];
        float Hc = rp[0] * wx[0] + c0 * wx[1] + rp[2] * wx[2];

        #pragma unroll
        for (int r = 0; r < 16; ++r) {
            const int row = y0 + r;
            rp = &sb[(row + 2) * SCOLS + x];   // tile row row+2 (= output row row+1)
            const float e0 = rp[0], e1 = rp[1], e2 = rp[2];
            const float Hp = e0 * wx[0] + e1 * wx[1] + e2 * wx[2];
            o0[row * W_ + x] = c0;
            o1[row * W_ + x] = Hm * wy[0] + Hc * wy[1] + Hp * wy[2];
            Hm = Hc; Hc = Hp; c0 = e1;
        }

        // Drain next plane's registers into the other buffer, then barrier.
        if (i < 7) {
            float* __restrict__ sw = s[(i + 1) & 1];
            #pragma unroll
            for (int k = 0; k < 16; ++k) {
                const int y = (k << 2) + wv;
                sw[(y + 1) * SCOLS + 1 + lane] = v[k];
            }
            __syncthreads();
        }
    }
}

extern "C" void kernel_launch(void* const* d_in, const int* in_sizes, int n_in,
                              void* d_out, int out_size, void* d_ws, size_t ws_size,
                              hipStream_t stream) {
    const float* inp    = (const float*)d_in[0];
    const float* offset = (const float*)d_in[1];
    float* out0 = (float*)d_out;
    float* out1 = out0 + (size_t)B_ * C_ * PLANE;
    displace_fused_pipe<<<B_ * G_, 256, 0, stream>>>(inp, offset, out0, out1);
}

// Round 7
// 266.762 us; speedup vs baseline: 1.0251x; 1.0231x over previous
//
#include <hip/hip_runtime.h>

// Problem: B=16, C=384, H=W=64, G=48 groups (8 ch/group), K=3 gaussian, sigma=0.5
#define B_   16
#define C_   384
#define H_   64
#define W_   64
#define G_   48
#define PLANE (H_ * W_)   // 4096

// No-LDS, no-barrier version. One block per plane (grid = B*C = 6144).
// lane = output column, wave wv handles output rows y0..y0+15. Displaced
// rows y0-1..y0+16 live in an 18-deep register ring (all 18 loads issued
// before any consumer; 32 waves/CU since LDS=0). Horizontal 3-tap via
// cross-lane shuffles executed UNCONDITIONALLY (ds_bpermute is convergent;
// putting it behind a lane-dependent branch makes reads from exec-masked
// lanes return garbage — that was R6's bug). Edge zero-patch applied to the
// shuffle RESULT with a branchless select. No __syncthreads anywhere.
__global__ __launch_bounds__(256) void displace_fused_shfl(
    const float* __restrict__ inp,     // [B,C,H,W]
    const float* __restrict__ offset,  // [G,2] (x,y)
    float* __restrict__ out0,          // displaced
    float* __restrict__ out1)          // blurred
{
    const int tid = threadIdx.x;
    const int p   = blockIdx.x;          // plane in [0, B*C)
    const int g   = (p % C_) >> 3;       // 8 channels per group

    const float ofx = offset[2 * g + 0];
    const float ofy = offset[2 * g + 1];
    const float rx = rintf(ofx);      // half-even == jnp.round; no ties (noise ±0.45)
    const float ry = rintf(ofy);
    const float fx = ofx - rx;
    const float fy = ofy - ry;
    const int ox = (int)rx;
    const int oy = (int)ry;

    // Separable, separately-normalized gaussian: kern[i][j]/sum = wy[i]*wx[j]
    float wx[3], wy[3];
    {
        float sxs = 0.0f, sys = 0.0f;
        #pragma unroll
        for (int j = 0; j < 3; ++j) {
            const float dx = (float)(j - 1) + fx;
            const float dy = (float)(j - 1) + fy;
            wx[j] = __expf(-dx * dx * 2.0f);   // 1/(2*sigma^2) = 2
            wy[j] = __expf(-dy * dy * 2.0f);
            sxs += wx[j]; sys += wy[j];
        }
        const float ix = 1.0f / sxs, iy = 1.0f / sys;
        #pragma unroll
        for (int j = 0; j < 3; ++j) { wx[j] *= ix; wy[j] *= iy; }
    }

    const int lane = tid & 63;           // output column
    const int wv   = tid >> 6;           // wave id 0..3
    const int y0   = wv << 4;            // first output row of this wave
    const int sx   = lane - ox;
    const bool vx  = (unsigned)sx < (unsigned)W_;

    const float* __restrict__ plane = inp + (size_t)p * PLANE;

    // Displaced rows y0-1 .. y0+16. Rows outside [0,64) are conv zero-pad;
    // rows whose source (y-oy) is OOB are displacement zero-pad.
    float v[18];
    #pragma unroll
    for (int k = 0; k < 18; ++k) {
        const int y  = y0 - 1 + k;
        const int sy = y - oy;
        v[k] = (vx && (unsigned)y < (unsigned)H_ && (unsigned)sy < (unsigned)H_)
                 ? plane[sy * W_ + sx] : 0.0f;
    }

    // Horizontal 3-tap per displaced row. Shuffles run with ALL lanes active;
    // edge lanes patched afterwards via branchless select (v_cndmask).
    float Hh[18];
    #pragma unroll
    for (int k = 0; k < 18; ++k) {
        const float su = __shfl_up(v[k], 1, 64);     // unconditional
        const float sd = __shfl_down(v[k], 1, 64);   // unconditional
        const float L = (lane == 0)  ? 0.0f : su;
        const float R = (lane == 63) ? 0.0f : sd;
        Hh[k] = L * wx[0] + v[k] * wx[1] + R * wx[2];
    }

    float* __restrict__ o0 = out0 + (size_t)p * PLANE + y0 * W_ + lane;
    float* __restrict__ o1 = out1 + (size_t)p * PLANE + y0 * W_ + lane;

    #pragma unroll
    for (int r = 0; r < 16; ++r) {
        o0[r * W_] = v[r + 1];                                        // displaced
        o1[r * W_] = Hh[r] * wy[0] + Hh[r + 1] * wy[1] + Hh[r + 2] * wy[2];
    }
}

extern "C" void kernel_launch(void* const* d_in, const int* in_sizes, int n_in,
                              void* d_out, int out_size, void* d_ws, size_t ws_size,
                              hipStream_t stream) {
    const float* inp    = (const float*)d_in[0];
    const float* offset = (const float*)d_in[1];
    float* out0 = (float*)d_out;
    float* out1 = out0 + (size_t)B_ * C_ * PLANE;
    displace_fused_shfl<<<B_ * C_, 256, 0, stream>>>(inp, offset, out0, out1);
}